// Round 5
// baseline (350.704 us; speedup 1.0000x reference)
//
#include <hip/hip_runtime.h>

// BLAMem: truncated tensor-algebra (depth 4, C=8) log-signature memory.
// Round-12: fused kernel, SYSTEM-scope (sc0 sc1) coherent barriers + data.
// Evidence trail: R9 fetch_add barrier 228us; R10 flag+fence barrier 206us
// (=> ~40us/barrier = the agent fences' buffer_wbl2/inv sweeps). R11 removed the
// fences but polled with AGENT-scope relaxed loads (global_load sc1): sc1 bypasses
// L2 but NOT the per-CU L1 -> poll spins on a stale L1 line forever -> HANG
// (container killed twice). THIS round: SYSTEM scope everywhere (sc0 sc1 = bypass
// L1 AND L2, no fence instructions at all). Explicit s_waitcnt(0) before arrival
// provides write-visibility ordering. Every poll has a ~40ms s_memrealtime timeout:
// deadlock now => wrong-answer diagnosis, not a hung container.
// Also: phases 4+5 merged (8 blocks: pooled->LDS, full gemv with bit-identical
// per-32-chunk FP grouping, ReLU, W2, tree-reduce) => 3 barriers, no hpart buffer;
// blocks >=8 arrive-and-exit at the last barrier.
// Carried: NO atomic RMW anywhere; LDS rows padded to stride 9; FP summation order
// bit-identical to the verified round-0..3 kernels.

#define MEM   4680   // 8 + 64 + 512 + 4096 (unpadded global layout)
#define NG    32     // groups per batch
#define TLEN  2048
#define NBLK  256

#define P3OFF 72
#define P4OFF 648
#define SIGSZ 5256

// Coherence-point scalar accessors (SYSTEM scope => global_load/store sc0 sc1:
// bypasses L1 and L2 on both sides; no fences, no wb, no inv).
__device__ __forceinline__ float ldc(const float* p) {
    return __hip_atomic_load(p, __ATOMIC_RELAXED, __HIP_MEMORY_SCOPE_SYSTEM);
}
__device__ __forceinline__ void stc(float* p, float v) {
    __hip_atomic_store(p, v, __ATOMIC_RELAXED, __HIP_MEMORY_SCOPE_SYSTEM);
}
__device__ __forceinline__ unsigned ldu(const unsigned* p) {
    return __hip_atomic_load(p, __ATOMIC_RELAXED, __HIP_MEMORY_SCOPE_SYSTEM);
}
__device__ __forceinline__ void stu(unsigned* p, unsigned v) {
    __hip_atomic_store(p, v, __ATOMIC_RELAXED, __HIP_MEMORY_SCOPE_SYSTEM);
}

#define SPIN_TIMEOUT 4000000ull   // s_memrealtime ticks (~40ms @100MHz)

// Fence-free grid barrier, generation k = 1,2,3,... (flags/gen zeroed pre-launch).
// Arrival: leader stores k to flags[bid] (own word, write-through to coherence
// point). Detection: block 0's 256 threads poll one flag each (sc0 sc1 loads are
// always fresh). Publication: gen. s_waitcnt(0) before s_barrier guarantees each
// wave's coherent stores are ack'd at the coherence point before the flag store.
// wait_release=false: arrive only (for blocks with no further work).
__device__ __forceinline__ void grid_barrier(unsigned* flags, unsigned* gen,
                                             unsigned k, bool wait_release) {
    __builtin_amdgcn_s_waitcnt(0);
    __syncthreads();
    const int tid = threadIdx.x;
    if (blockIdx.x == 0) {
        if (tid == 0) stu(&flags[0], k);
        unsigned long long t0 = __builtin_amdgcn_s_memrealtime();
        while (ldu(&flags[tid]) < k) {
            __builtin_amdgcn_s_sleep(4);
            if (__builtin_amdgcn_s_memrealtime() - t0 > SPIN_TIMEOUT) break;
        }
        __syncthreads();
        if (tid == 0) stu(gen, k);
    } else {
        if (tid == 0) {
            stu(&flags[blockIdx.x], k);
            if (wait_release) {
                unsigned long long t0 = __builtin_amdgcn_s_memrealtime();
                while (ldu(gen) < k) {
                    __builtin_amdgcn_s_sleep(4);
                    if (__builtin_amdgcn_s_memrealtime() - t0 > SPIN_TIMEOUT) break;
                }
            }
        }
        __syncthreads();
    }
}

__global__ __launch_bounds__(256) void fused_kernel(
    const float* __restrict__ x,  const float* __restrict__ W1,
    const float* __restrict__ b1, const float* __restrict__ W2,
    const float* __restrict__ b2, float* __restrict__ outp,
    float* __restrict__ T, float* __restrict__ P,
    float* __restrict__ partial,
    unsigned* __restrict__ barflags, unsigned* __restrict__ bargen)
{
    const int bid = blockIdx.x;
    const int tid = threadIdx.x;
    const int b = bid >> 5, g = bid & 31;

    __shared__ __attribute__((aligned(16))) float sSnap[4][SIGSZ];   // 84.1 KB
    __shared__ __attribute__((aligned(16))) float sInc[512];
    __shared__ __attribute__((aligned(16))) float U[648];   // loc3 576 | loc2 64 | loc1 8
    __shared__ __attribute__((aligned(16))) float sR[648];
    __shared__ float st1[NG][8];
    __shared__ float st2[NG][64];
    __shared__ float st3[NG][32];
    __shared__ float sp1[NG][8];
    __shared__ float sp2[NG][64];
    __shared__ float sp3[NG][32];
    __shared__ __attribute__((aligned(16))) float sPool[MEM];  // 18.7 KB (phase 4)
    __shared__ float sRed[256];

    const int i1 = tid >> 6, j1 = (tid >> 3) & 7, k1 = tid & 7;
    const int row1 = tid >> 3, row2 = row1 + 32;
    const int jk = tid & 63;
    const int pos2 = tid + 256, i2 = pos2 >> 6;

    float* loc3 = U;
    float* loc2 = U + 576;
    float* loc1 = U + 640;

    // ---------------- phase 1: per-group Chen fold, snapshots kept in LDS -------
    for (int e = tid; e < 512; e += 256) {
        int s = e >> 3, c = e & 7;
        int t = g * 64 + s;
        float v;
        if (c < 7) {
            float cur  = x[(b * TLEN + t) * 7 + c];
            float prev = (t > 0) ? x[(b * TLEN + t - 1) * 7 + c] : 0.f;
            v = cur - prev;
        } else v = (t > 0) ? (1.f / 2047.f) : 0.f;
        sInc[e] = v;
    }
    __syncthreads();

    for (int c = 0; c < 4; ++c) {
        const float* dch = &sInc[c * 128];
        float p1a = 0.f, l2a = 0.f, l3a = 0.f, p1b = 0.f, l2b = 0.f, l3b = 0.f;
        float Sa[8], Sb[8];
#pragma unroll
        for (int l = 0; l < 8; l++) { Sa[l] = 0.f; Sb[l] = 0.f; }
#pragma unroll
        for (int t = 0; t < 16; t++) {
            const float* dr = dch + t * 8;
            float di1 = dr[i1], di2 = dr[i2], dj = dr[j1], dk = dr[k1];
            float ga = l3a + dk * (l2a * 0.5f + dj * (p1a * (1.f/6.f) + di1 * (1.f/24.f)));
            float gb = l3b + dk * (l2b * 0.5f + dj * (p1b * (1.f/6.f) + di2 * (1.f/24.f)));
#pragma unroll
            for (int l = 0; l < 8; l++) { float dv = dr[l]; Sa[l] += ga * dv; Sb[l] += gb * dv; }
            l3a += dk * (l2a + dj * (p1a * 0.5f + di1 * (1.f/6.f)));
            l3b += dk * (l2b + dj * (p1b * 0.5f + di2 * (1.f/6.f)));
            l2a += (p1a + di1 * 0.5f) * dj;
            l2b += (p1b + di2 * 0.5f) * dj;
            p1a += di1; p1b += di2;
        }
        loc3[row1 * 9 + k1] = l3a;
        loc3[row2 * 9 + k1] = l3b;
        if (k1 == 0) { loc2[row1] = l2a; loc2[row2] = l2b; }
        if (jk == 0) { loc1[i1] = p1a; loc1[i2] = p1b; }
        __syncthreads();

        float* dst = sSnap[c];
        const float* l3p = &loc3[jk * 9];
        const float* l2p = &loc2[k1 * 8];
        if (c == 0) {
#pragma unroll
            for (int l = 0; l < 8; l++) { dst[P4OFF + tid * 9 + l] = Sa[l]; dst[P4OFF + pos2 * 9 + l] = Sb[l]; }
            dst[P3OFF + row1 * 9 + k1] = l3a;
            dst[P3OFF + row2 * 9 + k1] = l3b;
            if (tid < 64) dst[8 + tid] = loc2[tid];
            if (tid < 8)  dst[tid] = loc1[tid];
        } else {
            const float* prv = sSnap[c - 1];
            float a1 = prv[i1], a2 = prv[8 + row1], a3 = prv[P3OFF + row1 * 9 + k1];
            float c1_ = prv[i2], c2_ = prv[8 + row2], c3_ = prv[P3OFF + row2 * 9 + k1];
#pragma unroll
            for (int l = 0; l < 8; l++) {
                float v3 = l3p[l], v2 = l2p[l], v1 = loc1[l];
                dst[P4OFF + tid * 9 + l]  = prv[P4OFF + tid * 9 + l]  + Sa[l] + a1 * v3 + a2 * v2 + a3 * v1;
                dst[P4OFF + pos2 * 9 + l] = prv[P4OFF + pos2 * 9 + l] + Sb[l] + c1_ * v3 + c2_ * v2 + c3_ * v1;
            }
            dst[P3OFF + row1 * 9 + k1] = a3 + l3a + a1 * loc2[jk] + a2 * loc1[k1];
            dst[P3OFF + row2 * 9 + k1] = c3_ + l3b + c1_ * loc2[jk] + c2_ * loc1[k1];
            if (tid < 64) dst[8 + tid] = prv[8 + tid] + loc2[tid] + prv[tid >> 3] * loc1[tid & 7];
            if (tid < 8)  dst[tid] = prv[tid] + loc1[tid];
        }
        __syncthreads();
    }

    // write group totals (snapshot 3), coherent scalar stores
    {
        const float* s3 = sSnap[3];
        float* Tr = T + (size_t)bid * MEM;
        for (int m = tid; m < MEM; m += 256) {
            float v;
            if (m < 72) v = s3[m];
            else if (m < 584) { int e = m - 72;  v = s3[P3OFF + (e >> 3) * 9 + (e & 7)]; }
            else              { int e = m - 584; v = s3[P4OFF + (e >> 3) * 9 + (e & 7)]; }
            stc(Tr + m, v);
        }
    }

    grid_barrier(barflags, bargen, 1u, true);

    // ---------------- phase 2: cross-group cascade scan (blocks 0..127) ---------
    if (bid < 128) {
        const int b2 = bid >> 4, s = bid & 15;
        const int bBase = b2 * NG;
        const int jkl   = ((s & 1) << 8) | tid;
        const int m4idx = s * 256 + tid;

        float rL4[NG], rL3[NG];
#pragma unroll
        for (int gg = 0; gg < NG; gg++) {
            const float* Trow = T + (size_t)(bBase + gg) * MEM;
            rL4[gg] = ldc(Trow + 584 + m4idx);
            rL3[gg] = ldc(Trow + 72 + jkl);
        }
        {
            int gg = tid >> 3, i = tid & 7;
            st1[gg][i] = ldc(T + (size_t)(bBase + gg) * MEM + i);
        }
        for (int m = tid; m < NG * 64; m += 256) {
            int gg = m >> 6, e = m & 63;
            st2[gg][e] = ldc(T + (size_t)(bBase + gg) * MEM + 8 + e);
        }
        for (int m = tid; m < NG * 32; m += 256) {
            int gg = m >> 5, e = m & 31;
            st3[gg][e] = ldc(T + (size_t)(bBase + gg) * MEM + 72 + s * 32 + e);
        }
        __syncthreads();

        if (tid < 64) {
            int i = tid >> 3, k = tid & 7;
            float p1acc = 0.f, p2acc = 0.f;
            for (int gg = 0; gg < NG; gg++) {
                sp2[gg][tid] = p2acc;
                if (k == 0) sp1[gg][i] = p1acc;
                if (s == 0) {
                    float* prow = P + (size_t)(bBase + gg) * MEM;
                    stc(prow + 8 + tid, p2acc);
                    if (k == 0) stc(prow + i, p1acc);
                }
                p2acc += st2[gg][tid] + p1acc * st1[gg][k];
                p1acc += st1[gg][i];
            }
        }
        __syncthreads();
        if (tid < 32) {
            int ijk = s * 32 + tid;
            int i = ijk >> 6, jk2 = ijk & 63, ij = ijk >> 3, k = ijk & 7;
            float acc3 = 0.f;
            for (int gg = 0; gg < NG; gg++) {
                sp3[gg][tid] = acc3;
                stc(P + (size_t)(bBase + gg) * MEM + 72 + ijk, acc3);
                acc3 += st3[gg][tid] + sp1[gg][i] * st2[gg][jk2] + sp2[gg][ij] * st1[gg][k];
            }
        }
        __syncthreads();
        {
            const int i  = s >> 1;
            const int ij = (s << 2) + (tid >> 6);
            const int kl = tid & 63, l = tid & 7, p3 = tid >> 3;
            float acc4 = 0.f;
            size_t prowBase = (size_t)bBase * MEM + 584 + m4idx;
#pragma unroll
            for (int gg = 0; gg < NG; gg++) {
                stc(P + prowBase + (size_t)gg * MEM, acc4);
                acc4 += rL4[gg] + sp1[gg][i] * rL3[gg] + sp2[gg][ij] * st2[gg][kl] + sp3[gg][p3] * st1[gg][l];
            }
        }
    }

    grid_barrier(barflags, bargen, 2u, true);

    // ---------------- phase 3: apply prefix + log + pool (snapshots from LDS) ---
    {
        const float* Prow = P + (size_t)bid * MEM;
        const float a1  = ldc(Prow + i1);
        const float a2  = ldc(Prow + 8 + row1);
        const float a3  = ldc(Prow + 72 + tid);
        const float c1_ = ldc(Prow + i2);
        const float c2_ = ldc(Prow + 8 + row2);
        const float c3_ = ldc(Prow + 72 + 256 + tid);
        float pP4a[8], pP4b[8];
#pragma unroll
        for (int l = 0; l < 8; l++) {
            pP4a[l] = ldc(Prow + 584 + tid * 8 + l);
            pP4b[l] = ldc(Prow + 584 + (tid + 256) * 8 + l);
        }
        const float p2v = (tid < 64) ? ldc(Prow + 8 + tid) : 0.f;
        const float p1v = (tid < 8) ? ldc(Prow + tid) : 0.f;
        const float p2i = ldc(Prow + (tid >> 3));

        float pool4a[8], pool4b[8];
#pragma unroll
        for (int l = 0; l < 8; l++) { pool4a[l] = 0.f; pool4b[l] = 0.f; }
        float pool3a = 0.f, pool3b = 0.f, pool2 = 0.f, pool1 = 0.f;

        for (int c = 0; c < 4; ++c) {
            const float* sAc = sSnap[c];
            const float* q3p = &sAc[P3OFF + jk * 9];
            const float* q2p = &sAc[8 + k1 * 8];
            float R4a[8], R4b[8];
#pragma unroll
            for (int l = 0; l < 8; l++) {
                float v3 = q3p[l], v2 = q2p[l], v1 = sAc[l];
                R4a[l] = pP4a[l] + sAc[P4OFF + tid * 9 + l]  + a1 * v3 + a2 * v2 + a3 * v1;
                R4b[l] = pP4b[l] + sAc[P4OFF + pos2 * 9 + l] + c1_ * v3 + c2_ * v2 + c3_ * v1;
            }
            float R3a = a3  + sAc[P3OFF + row1 * 9 + k1] + a1  * sAc[8 + jk] + a2  * sAc[k1];
            float R3b = c3_ + sAc[P3OFF + row2 * 9 + k1] + c1_ * sAc[8 + jk] + c2_ * sAc[k1];
            float R2v = 0.f, R1v = 0.f;
            if (tid < 64) R2v = p2v + sAc[8 + tid] + p2i * sAc[tid & 7];
            if (tid < 8)  R1v = p1v + sAc[tid];

            sR[P3OFF + row1 * 9 + k1] = R3a;
            sR[P3OFF + row2 * 9 + k1] = R3b;
            if (tid < 64) sR[8 + tid] = R2v;
            if (tid < 8)  sR[tid] = R1v;
            __syncthreads();

            float q23a = sR[i1] * sR[8 + jk] + sR[8 + row1] * sR[k1];
            float q23b = sR[i2] * sR[8 + jk] + sR[8 + row2] * sR[k1];
            {
                float s1ia = sR[i1], s1ib = sR[i2], s1j = sR[j1], s1k = sR[k1];
                float s2ija = sR[8 + row1], s2ijb = sR[8 + row2];
                float s2jk = sR[8 + jk];
                const float* r3p = &sR[P3OFF + jk * 9];
                const float* r2p = &sR[8 + k1 * 8];
#pragma unroll
                for (int l = 0; l < 8; l++) {
                    float s1l = sR[l];
                    float p22 = s1k * s1l;
                    float q23l = s1j * r2p[l] + s2jk * s1l;
                    float p24a = s1ia * r3p[l] + s2ija * r2p[l] + R3a * s1l;
                    float p24b = s1ib * r3p[l] + s2ijb * r2p[l] + R3b * s1l;
                    float p34a = s1ia * q23l + s2ija * p22;
                    float p34b = s1ib * q23l + s2ijb * p22;
                    float p44a = s1ia * s1j * p22;
                    float p44b = s1ib * s1j * p22;
                    pool4a[l] += R4a[l] - 0.5f * p24a + (1.f/3.f) * p34a - 0.25f * p44a;
                    pool4b[l] += R4b[l] - 0.5f * p24b + (1.f/3.f) * p34b - 0.25f * p44b;
                }
                pool3a += R3a - 0.5f * q23a + (1.f/3.f) * s1ia * s1j * s1k;
                pool3b += R3b - 0.5f * q23b + (1.f/3.f) * s1ib * s1j * s1k;
                if (tid < 64) pool2 += R2v - 0.5f * sR[tid >> 3] * sR[tid & 7];
                if (tid < 8)  pool1 += R1v;
            }
            __syncthreads();
        }

        float* pb = partial + (size_t)bid * MEM;
#pragma unroll
        for (int l = 0; l < 8; l++) {
            stc(pb + 584 + tid * 8 + l, pool4a[l]);
            stc(pb + 584 + (tid + 256) * 8 + l, pool4b[l]);
        }
        stc(pb + 72 + tid, pool3a);
        stc(pb + 72 + 256 + tid, pool3b);
        if (tid < 64) stc(pb + 8 + tid, pool2);
        if (tid < 8)  stc(pb + tid, pool1);
    }

    // Blocks >=8 arrive and exit; blocks 0..7 continue to the merged gemv+MLP.
    grid_barrier(barflags, bargen, 3u, bid < 8);
    if (bid >= 8) return;

    // ---------------- phase 4+5 merged: pooled -> gemv -> MLP (blocks 0..7) -----
    {
        for (int m = tid; m < MEM; m += 256) {
            float sum = 0.f;
            for (int gg = 0; gg < NG; gg++)
                sum += ldc(partial + (size_t)(bid * NG + gg) * MEM + m);
            sPool[m] = sum * (1.f / 128.f);
        }
        __syncthreads();
        // gemv, bit-identical grouping to the verified split kernels:
        // per-32-chunk inner accumulation, chunks added in ascending order.
        float v = 0.f;
        for (int kc = 0; kc < 147; kc++) {
            const int k0 = kc * 32;
            const int kend = (k0 + 32 < MEM) ? 32 : (MEM - k0);
            float acc = 0.f;
            for (int k = 0; k < kend; k++)
                acc += sPool[k0 + k] * W1[(size_t)(k0 + k) * 256 + tid];
            v += acc;
        }
        v += b1[tid];
        v = fmaxf(v, 0.f) * W2[tid];
        sRed[tid] = v;
        __syncthreads();
        for (int s = 128; s > 0; s >>= 1) {
            if (tid < s) sRed[tid] += sRed[tid + s];
            __syncthreads();
        }
        if (tid == 0) outp[bid] = sRed[0] + b2[0];
    }
}

// ------------------------------------------------ launch
extern "C" void kernel_launch(void* const* d_in, const int* in_sizes, int n_in,
                              void* d_out, int out_size, void* d_ws, size_t ws_size,
                              hipStream_t stream) {
    const float* x  = (const float*)d_in[0];
    const float* W1 = (const float*)d_in[1];
    const float* b1 = (const float*)d_in[2];
    const float* W2 = (const float*)d_in[3];
    const float* b2 = (const float*)d_in[4];
    float* out = (float*)d_out;

    float* ws = (float*)d_ws;
    float* T       = ws;                            // 256*MEM (group totals, compact)
    float* P       = T + (size_t)256 * MEM;         // 256*MEM (exclusive group prefixes)
    float* partial = P + (size_t)256 * MEM;         // 256*MEM (per-group pooled rows)
    size_t baroff = (size_t)256 * MEM * 3;
    baroff = (baroff + 31) & ~(size_t)31;           // 128B-align barrier region
    unsigned* barflags = (unsigned*)(ws + baroff);  // flags[256]
    unsigned* bargen   = barflags + 288;            // own 128B line

    // workspace is poisoned each iteration: flags and gen MUST be zeroed.
    hipMemsetAsync(barflags, 0, 1280, stream);
    fused_kernel<<<NBLK, 256, 0, stream>>>(x, W1, b1, W2, b2, out, T, P, partial,
                                           barflags, bargen);
}

// Round 6
// 130.245 us; speedup vs baseline: 2.6926x; 2.6926x over previous
//
#include <hip/hip_runtime.h>

// BLAMem: truncated tensor-algebra (depth 4, C=8) log-signature memory.
// Round-13: REVERT to the verified R1 5-kernel pipeline (124.9us), minus one
// dispatch: k1+k2 merged via a PER-BATCH producer-flag sync (not a grid barrier).
// Fused-arc post-mortem (R9-R12): grid barriers cost ~45us each fenced (L2 wb/inv
// sweeps); fence-free needs cache-bypass data paths which, combined with 1 blk/CU
// and an 8-block tail phase (per-CU load-throughput ceiling ~64B/cy), lost 100+us.
// Here the only cross-block handoff inside a kernel is fold->scan totals: written
// write-through (sc0 sc1, correctness proven in R12/absmax 0), flagged after
// __syncthreads (drains all waves' vmcnt), polled with timeout (no hang mode).
// P / S / partial / hpart cross KERNEL boundaries -> runtime dispatch-level
// coherence; plain cached loads/stores (the fast path, as in R1).
// Carried: NO atomic RMW; LDS rows padded to stride 9; FP summation orders
// bit-identical to the verified round-0/1 kernels.

#define MEM   4680   // 8 + 64 + 512 + 4096 (unpadded global layout)
#define NG    32     // groups per batch
#define TLEN  2048

#define P3OFF 72
#define P4OFF 648
#define SIGSZ 5256

// Coherence-point accessors (SYSTEM scope => sc0 sc1: bypass L1+L2, no fences).
__device__ __forceinline__ float ldc(const float* p) {
    return __hip_atomic_load(p, __ATOMIC_RELAXED, __HIP_MEMORY_SCOPE_SYSTEM);
}
__device__ __forceinline__ void stc(float* p, float v) {
    __hip_atomic_store(p, v, __ATOMIC_RELAXED, __HIP_MEMORY_SCOPE_SYSTEM);
}
__device__ __forceinline__ unsigned ldu(const unsigned* p) {
    return __hip_atomic_load(p, __ATOMIC_RELAXED, __HIP_MEMORY_SCOPE_SYSTEM);
}
__device__ __forceinline__ void stu(unsigned* p, unsigned v) {
    __hip_atomic_store(p, v, __ATOMIC_RELAXED, __HIP_MEMORY_SCOPE_SYSTEM);
}
#define SPIN_TIMEOUT 4000000ull   // s_memrealtime ticks (~40ms) — converts any
                                  // sync bug into a wrong-answer, never a hang.

// Load the 64 per-step increments for group (b,g) into sInc[512].
__device__ __forceinline__ void load_inc(const float* __restrict__ x, int b, int g,
                                         float* sInc, int tid) {
    for (int e = tid; e < 512; e += 256) {
        int s = e >> 3, c = e & 7;
        int t = g * 64 + s;
        float v;
        if (c < 7) {
            float cur  = x[(b * TLEN + t) * 7 + c];
            float prev = (t > 0) ? x[(b * TLEN + t - 1) * 7 + c] : 0.f;
            v = cur - prev;
        } else v = (t > 0) ? (1.f / 2047.f) : 0.f;
        sInc[e] = v;
    }
}

// Fold chunk-local signature (16 steps, closed form) into running padded product sA.
__device__ __forceinline__ void chunk_step(const float* dch, float* sA, float* U, int tid) {
    float* loc3 = U;
    float* loc2 = U + 576;
    float* loc1 = U + 640;
    const int i1 = tid >> 6, j1 = (tid >> 3) & 7, k1 = tid & 7;
    const int row1 = tid >> 3, row2 = row1 + 32;
    const int jk = tid & 63;
    const int pos2 = tid + 256, i2 = pos2 >> 6;
    float p1a = 0.f, l2a = 0.f, l3a = 0.f, p1b = 0.f, l2b = 0.f, l3b = 0.f;
    float Sa[8], Sb[8];
#pragma unroll
    for (int l = 0; l < 8; l++) { Sa[l] = 0.f; Sb[l] = 0.f; }
#pragma unroll
    for (int t = 0; t < 16; t++) {
        const float* dr = dch + t * 8;
        float di1 = dr[i1], di2 = dr[i2], dj = dr[j1], dk = dr[k1];
        float ga = l3a + dk * (l2a * 0.5f + dj * (p1a * (1.f/6.f) + di1 * (1.f/24.f)));
        float gb = l3b + dk * (l2b * 0.5f + dj * (p1b * (1.f/6.f) + di2 * (1.f/24.f)));
#pragma unroll
        for (int l = 0; l < 8; l++) { float dv = dr[l]; Sa[l] += ga * dv; Sb[l] += gb * dv; }
        l3a += dk * (l2a + dj * (p1a * 0.5f + di1 * (1.f/6.f)));
        l3b += dk * (l2b + dj * (p1b * 0.5f + di2 * (1.f/6.f)));
        l2a += (p1a + di1 * 0.5f) * dj;
        l2b += (p1b + di2 * 0.5f) * dj;
        p1a += di1; p1b += di2;
    }
    loc3[row1 * 9 + k1] = l3a;
    loc3[row2 * 9 + k1] = l3b;
    if (k1 == 0) { loc2[row1] = l2a; loc2[row2] = l2b; }
    if (jk == 0) { loc1[i1] = p1a; loc1[i2] = p1b; }
    __syncthreads();
    float a1 = sA[i1], a2 = sA[8 + row1], a3 = sA[P3OFF + row1 * 9 + k1];
    float c1_ = sA[i2], c2_ = sA[8 + row2], c3_ = sA[P3OFF + row2 * 9 + k1];
    const float* l3p = &loc3[jk * 9];
    const float* l2p = &loc2[k1 * 8];
    float n4a[8], n4b[8];
#pragma unroll
    for (int l = 0; l < 8; l++) {
        float v3 = l3p[l], v2 = l2p[l], v1 = loc1[l];
        n4a[l] = sA[P4OFF + tid * 9 + l]  + Sa[l] + a1 * v3 + a2 * v2 + a3 * v1;
        n4b[l] = sA[P4OFF + pos2 * 9 + l] + Sb[l] + c1_ * v3 + c2_ * v2 + c3_ * v1;
    }
    float n3a = a3 + l3a + a1 * loc2[jk] + a2 * loc1[k1];
    float n3b = c3_ + l3b + c1_ * loc2[jk] + c2_ * loc1[k1];
    float n2v = 0.f, n1v = 0.f;
    if (tid < 64) n2v = sA[8 + tid] + loc2[tid] + sA[tid >> 3] * loc1[tid & 7];
    if (tid < 8)  n1v = sA[tid] + loc1[tid];
    __syncthreads();
#pragma unroll
    for (int l = 0; l < 8; l++) { sA[P4OFF + tid * 9 + l] = n4a[l]; sA[P4OFF + pos2 * 9 + l] = n4b[l]; }
    sA[P3OFF + row1 * 9 + k1] = n3a;
    sA[P3OFF + row2 * 9 + k1] = n3b;
    if (tid < 64) sA[8 + tid] = n2v;
    if (tid < 8)  sA[tid] = n1v;
    __syncthreads();
}

// ------------------------------------------------ kernel 1: fold (blocks 0..255)
// + cascade scan (blocks 256..383), linked by a per-batch producer-flag sync.
__global__ __launch_bounds__(256) void fold_scan_kernel(const float* __restrict__ x,
                                                        float* __restrict__ S,
                                                        float* __restrict__ P,
                                                        unsigned* __restrict__ flags) {
    const int bid = blockIdx.x;
    const int tid = threadIdx.x;

    // fold-role LDS
    __shared__ __attribute__((aligned(16))) float sInc[512];
    __shared__ __attribute__((aligned(16))) float sA[SIGSZ];
    __shared__ __attribute__((aligned(16))) float U[648];
    // scan-role LDS
    __shared__ float st1[NG][8];
    __shared__ float st2[NG][64];
    __shared__ float st3[NG][32];
    __shared__ float sp1[NG][8];
    __shared__ float sp2[NG][64];
    __shared__ float sp3[NG][32];

    if (bid < 256) {
        // -------- fold role: per-group Chen fold, 4 cumulative snapshots --------
        const int b = bid >> 5, g = bid & 31;
        load_inc(x, b, g, sInc, tid);
        for (int m = tid; m < SIGSZ; m += 256) sA[m] = 0.f;
        __syncthreads();
        for (int c = 0; c < 4; c++) {
            chunk_step(&sInc[c * 128], sA, U, tid);
            // sA stable until the next chunk_step's second barrier: race-free reads.
            float* Sr = S + ((size_t)bid * 4 + c) * MEM;
            if (c < 3) {
                // consumed only by the NEXT KERNEL -> plain cached float4 stores
                for (int m4 = tid * 4; m4 < MEM; m4 += 1024) {
                    float4 v;
                    if (m4 < 72) {
                        v = make_float4(sA[m4], sA[m4 + 1], sA[m4 + 2], sA[m4 + 3]);
                    } else if (m4 < 584) {
                        int e = m4 - 72; const float* p0 = &sA[P3OFF + (e >> 3) * 9 + (e & 7)];
                        v = make_float4(p0[0], p0[1], p0[2], p0[3]);
                    } else {
                        int e = m4 - 584; const float* p0 = &sA[P4OFF + (e >> 3) * 9 + (e & 7)];
                        v = make_float4(p0[0], p0[1], p0[2], p0[3]);
                    }
                    *(float4*)(Sr + m4) = v;
                }
            } else {
                // c=3 snapshot (= group total) is consumed IN-KERNEL by scan blocks:
                // write-through stores (sc0 sc1) so no fence is needed for visibility.
                for (int m = tid; m < MEM; m += 256) {
                    float v;
                    if (m < 72) v = sA[m];
                    else if (m < 584) { int e = m - 72;  v = sA[P3OFF + (e >> 3) * 9 + (e & 7)]; }
                    else              { int e = m - 584; v = sA[P4OFF + (e >> 3) * 9 + (e & 7)]; }
                    stc(Sr + m, v);
                }
            }
        }
        __syncthreads();               // drains every wave's vmcnt (incl. stc stores)
        if (tid == 0) stu(&flags[bid], 1u);
        return;
    }

    // -------- scan role: cascade scan of batch b2's 32 group totals -> P --------
    const int sb = bid - 256;
    const int b2 = sb >> 4, s = sb & 15;
    const int bBase = b2 * NG;

    {   // wait for this batch's 32 fold blocks (8 threads poll each flag)
        const unsigned* f = flags + bBase + (tid & 31);
        unsigned long long t0 = __builtin_amdgcn_s_memrealtime();
        while (ldu(f) == 0u) {
            __builtin_amdgcn_s_sleep(4);
            if (__builtin_amdgcn_s_memrealtime() - t0 > SPIN_TIMEOUT) break;
        }
    }
    __syncthreads();

    const int jkl   = ((s & 1) << 8) | tid;   // (s*256+tid) & 511
    const int m4idx = s * 256 + tid;

    float rL4[NG], rL3[NG];
#pragma unroll
    for (int gg = 0; gg < NG; gg++) {
        const float* Trow = S + ((size_t)(bBase + gg) * 4 + 3) * MEM;
        rL4[gg] = ldc(Trow + 584 + m4idx);
        rL3[gg] = ldc(Trow + 72 + jkl);
    }
    {
        int gg = tid >> 3, i = tid & 7;
        st1[gg][i] = ldc(S + ((size_t)(bBase + gg) * 4 + 3) * MEM + i);
    }
    for (int m = tid; m < NG * 64; m += 256) {
        int gg = m >> 6, e = m & 63;
        st2[gg][e] = ldc(S + ((size_t)(bBase + gg) * 4 + 3) * MEM + 8 + e);
    }
    for (int m = tid; m < NG * 32; m += 256) {
        int gg = m >> 5, e = m & 31;
        st3[gg][e] = ldc(S + ((size_t)(bBase + gg) * 4 + 3) * MEM + 72 + s * 32 + e);
    }
    __syncthreads();

    if (tid < 64) {
        int i = tid >> 3, k = tid & 7;
        float p1acc = 0.f, p2acc = 0.f;
        for (int gg = 0; gg < NG; gg++) {
            sp2[gg][tid] = p2acc;
            if (k == 0) sp1[gg][i] = p1acc;
            if (s == 0) {
                size_t prow = (size_t)(bBase + gg) * MEM;
                P[prow + 8 + tid] = p2acc;
                if (k == 0) P[prow + i] = p1acc;
            }
            p2acc += st2[gg][tid] + p1acc * st1[gg][k];
            p1acc += st1[gg][i];
        }
    }
    __syncthreads();
    if (tid < 32) {
        int ijk = s * 32 + tid;
        int i = ijk >> 6, jk2 = ijk & 63, ij = ijk >> 3, k = ijk & 7;
        float acc3 = 0.f;
        for (int gg = 0; gg < NG; gg++) {
            sp3[gg][tid] = acc3;
            P[(size_t)(bBase + gg) * MEM + 72 + ijk] = acc3;
            acc3 += st3[gg][tid] + sp1[gg][i] * st2[gg][jk2] + sp2[gg][ij] * st1[gg][k];
        }
    }
    __syncthreads();
    {
        const int i  = s >> 1;
        const int ij = (s << 2) + (tid >> 6);
        const int kl = tid & 63, l = tid & 7, p3 = tid >> 3;
        float acc4 = 0.f;
        size_t prowBase = (size_t)bBase * MEM + 584 + m4idx;
#pragma unroll
        for (int gg = 0; gg < NG; gg++) {
            P[prowBase + (size_t)gg * MEM] = acc4;
            acc4 += rL4[gg] + sp1[gg][i] * rL3[gg] + sp2[gg][ij] * st2[gg][kl] + sp3[gg][p3] * st1[gg][l];
        }
    }
}

// ------------------------------------------------ kernel 2: per-chunk apply + log +
// pool. 1024 blocks = one per (b,g,chunk). Byte-identical to verified R1 kernel.
__global__ __launch_bounds__(256, 3) void apply_log_pool_kernel(const float* __restrict__ P,
                                                                const float* __restrict__ S,
                                                                float* __restrict__ partial) {
    int blk = blockIdx.x;                 // = (b*32+g)*4 + c
    int tid = threadIdx.x;

    __shared__ __attribute__((aligned(16))) float sA[SIGSZ];
    __shared__ __attribute__((aligned(16))) float sR[648];

    const float* Prow = P + (size_t)(blk >> 2) * MEM;
    const float* Srow = S + (size_t)blk * MEM;

    const int i1 = tid >> 6, j1 = (tid >> 3) & 7, k1 = tid & 7;
    const int row1 = tid >> 3, row2 = row1 + 32;
    const int jk = tid & 63;
    const int pos2 = tid + 256, i2 = pos2 >> 6;

    float a1  = Prow[i1],        a2  = Prow[8 + row1], a3  = Prow[72 + tid];
    float c1_ = Prow[i2],        c2_ = Prow[8 + row2], c3_ = Prow[72 + 256 + tid];
    float4 pa0 = *(const float4*)(Prow + 584 + tid * 8);
    float4 pa1 = *(const float4*)(Prow + 584 + tid * 8 + 4);
    float4 pb0 = *(const float4*)(Prow + 584 + (tid + 256) * 8);
    float4 pb1 = *(const float4*)(Prow + 584 + (tid + 256) * 8 + 4);

    for (int m4 = tid * 4; m4 < MEM; m4 += 1024) {
        const float4 v = *(const float4*)(Srow + m4);
        float* d;
        if (m4 < 72) d = &sA[m4];
        else if (m4 < 584) { int e = m4 - 72;  d = &sA[P3OFF + (e >> 3) * 9 + (e & 7)]; }
        else               { int e = m4 - 584; d = &sA[P4OFF + (e >> 3) * 9 + (e & 7)]; }
        d[0] = v.x; d[1] = v.y; d[2] = v.z; d[3] = v.w;
    }
    __syncthreads();

    const float* q3p = &sA[P3OFF + jk * 9];
    const float* q2p = &sA[8 + k1 * 8];
    float pP4a[8] = {pa0.x, pa0.y, pa0.z, pa0.w, pa1.x, pa1.y, pa1.z, pa1.w};
    float pP4b[8] = {pb0.x, pb0.y, pb0.z, pb0.w, pb1.x, pb1.y, pb1.z, pb1.w};
    float R4a[8], R4b[8];
#pragma unroll
    for (int l = 0; l < 8; l++) {
        float v3 = q3p[l], v2 = q2p[l], v1 = sA[l];
        R4a[l] = pP4a[l] + sA[P4OFF + tid * 9 + l]  + a1 * v3 + a2 * v2 + a3 * v1;
        R4b[l] = pP4b[l] + sA[P4OFF + pos2 * 9 + l] + c1_ * v3 + c2_ * v2 + c3_ * v1;
    }
    float R3a = a3  + sA[P3OFF + row1 * 9 + k1] + a1  * sA[8 + jk] + a2  * sA[k1];
    float R3b = c3_ + sA[P3OFF + row2 * 9 + k1] + c1_ * sA[8 + jk] + c2_ * sA[k1];
    float R2v = 0.f, R1v = 0.f;
    if (tid < 64) R2v = Prow[8 + tid] + sA[8 + tid] + Prow[tid >> 3] * sA[tid & 7];
    if (tid < 8)  R1v = Prow[tid] + sA[tid];

    sR[P3OFF + row1 * 9 + k1] = R3a;
    sR[P3OFF + row2 * 9 + k1] = R3b;
    if (tid < 64) sR[8 + tid] = R2v;
    if (tid < 8)  sR[tid] = R1v;
    __syncthreads();

    float q23a = sR[i1] * sR[8 + jk] + sR[8 + row1] * sR[k1];
    float q23b = sR[i2] * sR[8 + jk] + sR[8 + row2] * sR[k1];
    float pool4a[8], pool4b[8];
    float pool3a, pool3b, pool2 = 0.f, pool1 = 0.f;
    {
        float s1ia = sR[i1], s1ib = sR[i2], s1j = sR[j1], s1k = sR[k1];
        float s2ija = sR[8 + row1], s2ijb = sR[8 + row2];
        float s2jk = sR[8 + jk];
        const float* r3p = &sR[P3OFF + jk * 9];
        const float* r2p = &sR[8 + k1 * 8];
#pragma unroll
        for (int l = 0; l < 8; l++) {
            float s1l = sR[l];
            float p22 = s1k * s1l;
            float q23l = s1j * r2p[l] + s2jk * s1l;
            float p24a = s1ia * r3p[l] + s2ija * r2p[l] + R3a * s1l;
            float p24b = s1ib * r3p[l] + s2ijb * r2p[l] + R3b * s1l;
            float p34a = s1ia * q23l + s2ija * p22;
            float p34b = s1ib * q23l + s2ijb * p22;
            float p44a = s1ia * s1j * p22;
            float p44b = s1ib * s1j * p22;
            pool4a[l] = R4a[l] - 0.5f * p24a + (1.f/3.f) * p34a - 0.25f * p44a;
            pool4b[l] = R4b[l] - 0.5f * p24b + (1.f/3.f) * p34b - 0.25f * p44b;
        }
        pool3a = R3a - 0.5f * q23a + (1.f/3.f) * s1ia * s1j * s1k;
        pool3b = R3b - 0.5f * q23b + (1.f/3.f) * s1ib * s1j * s1k;
        if (tid < 64) pool2 = R2v - 0.5f * sR[tid >> 3] * sR[tid & 7];
        if (tid < 8)  pool1 = R1v;
    }

    {
        float* pb = partial + (size_t)blk * MEM;
        *(float4*)(pb + 584 + tid * 8)     = make_float4(pool4a[0], pool4a[1], pool4a[2], pool4a[3]);
        *(float4*)(pb + 584 + tid * 8 + 4) = make_float4(pool4a[4], pool4a[5], pool4a[6], pool4a[7]);
        *(float4*)(pb + 584 + (tid + 256) * 8)     = make_float4(pool4b[0], pool4b[1], pool4b[2], pool4b[3]);
        *(float4*)(pb + 584 + (tid + 256) * 8 + 4) = make_float4(pool4b[4], pool4b[5], pool4b[6], pool4b[7]);
        pb[72 + tid] = pool3a;
        pb[72 + 256 + tid] = pool3b;
        if (tid < 64) pb[8 + tid] = pool2;
        if (tid < 8)  pb[tid] = pool1;
    }
}

// ------------------------------------------------ kernel 3: reduce 128 partial rows
// per batch + gemv -> hpart. Byte-identical to verified R1 kernel.
__global__ __launch_bounds__(256) void gemv1_kernel(const float* __restrict__ partial,
                                                    const float* __restrict__ W1,
                                                    float* __restrict__ hpart) {
    int kc = blockIdx.x;
    int tid = threadIdx.x;
    int k0 = kc * 32;
    __shared__ float sp[8][32];
    {
        int bb = tid >> 5, k = tid & 31;
        float sum = 0.f;
        if (k0 + k < MEM) {
            const float* pp = partial + (size_t)bb * 128 * MEM + k0 + k;
#pragma unroll 8
            for (int n = 0; n < 128; n++) sum += pp[(size_t)n * MEM];
        }
        sp[bb][k] = sum * (1.f / 128.f);
    }
    __syncthreads();
    float acc[8];
#pragma unroll
    for (int b = 0; b < 8; b++) acc[b] = 0.f;
    int kend = (k0 + 32 < MEM) ? 32 : (MEM - k0);
    for (int k = 0; k < kend; k++) {
        float wv = W1[(size_t)(k0 + k) * 256 + tid];
#pragma unroll
        for (int b = 0; b < 8; b++) acc[b] += sp[b][k] * wv;
    }
#pragma unroll
    for (int b = 0; b < 8; b++) hpart[(size_t)kc * 2048 + b * 256 + tid] = acc[b];
}

// ------------------------------------------------ kernel 4: reduce hpart + final MLP
__global__ __launch_bounds__(256) void final_kernel(const float* __restrict__ hpart,
                                                    const float* __restrict__ b1,
                                                    const float* __restrict__ W2,
                                                    const float* __restrict__ b2,
                                                    float* __restrict__ outp) {
    int b = blockIdx.x;
    int tid = threadIdx.x;
    float v = 0.f;
#pragma unroll 7
    for (int kc = 0; kc < 147; kc++) v += hpart[(size_t)kc * 2048 + b * 256 + tid];
    v += b1[tid];
    v = fmaxf(v, 0.f) * W2[tid];
    __shared__ float sRed[256];
    sRed[tid] = v;
    __syncthreads();
    for (int s = 128; s > 0; s >>= 1) {
        if (tid < s) sRed[tid] += sRed[tid + s];
        __syncthreads();
    }
    if (tid == 0) outp[b] = sRed[0] + b2[0];
}

// ------------------------------------------------ launch
extern "C" void kernel_launch(void* const* d_in, const int* in_sizes, int n_in,
                              void* d_out, int out_size, void* d_ws, size_t ws_size,
                              hipStream_t stream) {
    const float* x  = (const float*)d_in[0];
    const float* W1 = (const float*)d_in[1];
    const float* b1 = (const float*)d_in[2];
    const float* W2 = (const float*)d_in[3];
    const float* b2 = (const float*)d_in[4];
    float* out = (float*)d_out;

    float* ws = (float*)d_ws;
    float* S       = ws;                             // 1024*MEM (per-chunk cumulative sigs; c=3 = totals)
    float* P       = S + (size_t)1024 * MEM;         // 256*MEM  (exclusive group prefixes)
    float* partial = P + (size_t)256 * MEM;          // 1024*MEM (per-chunk pooled rows)
    float* hpart   = partial + (size_t)1024 * MEM;   // 147*2048 (gemv partials)
    size_t flagoff = (size_t)1024 * MEM * 2 + (size_t)256 * MEM + (size_t)147 * 2048;
    flagoff = (flagoff + 31) & ~(size_t)31;
    unsigned* flags = (unsigned*)(ws + flagoff);     // 256 per-group arrival flags

    // workspace is poisoned each iteration: flags MUST be zeroed. Stream-ordered.
    hipMemsetAsync(flags, 0, 1024, stream);
    fold_scan_kernel<<<384, 256, 0, stream>>>(x, S, P, flags);
    apply_log_pool_kernel<<<1024, 256, 0, stream>>>(P, S, partial);
    gemv1_kernel<<<147, 256, 0, stream>>>(partial, W1, hpart);
    final_kernel<<<8, 256, 0, stream>>>(hpart, b1, W2, b2, out);
}